// Round 15
// baseline (148.906 us; speedup 1.0000x reference)
//
#include <hip/hip_runtime.h>
#include <stdint.h>

#define DCAP   128
#define CHUNK  1024
#define LOG_TAB 18
#define TAB_SIZE (1u << LOG_TAB)
#define TAB_MASK (TAB_SIZE - 1u)
#define KEMPTY 0xFFFFFFFFu

typedef unsigned int uintv4 __attribute__((ext_vector_type(4)));

// 1) FUSED: in-degree (col) + undirected-dedup hash insert storing NODE ids
//    (pos resolved later in accum via broadcast L2 load).  [R14 exact]
__global__ void k_deg_ins(const int* __restrict__ ei, int* __restrict__ degree,
                          unsigned int* __restrict__ tab, int* __restrict__ uA,
                          int* __restrict__ uB, int* __restrict__ count, int E) {
    int e = blockIdx.x * blockDim.x + threadIdx.x;
    if (e >= E) return;
    int a = ei[e], b = ei[E + e];
    atomicAdd(&degree[b], 1);                      // bincount(edge_index[1])
    int r = min(a, b), c = max(a, b);
    unsigned int key = ((unsigned int)r << 16) | (unsigned int)c;  // N < 2^16
    unsigned int h = (key * 2654435761u) >> (32 - LOG_TAB);
    for (;;) {
        unsigned int old = atomicCAS(&tab[h], KEMPTY, key);
        if (old == KEMPTY) {                       // first occurrence
            int idx = atomicAdd(count, 1);
            uA[idx] = r; uB[idx] = c;
            return;
        }
        if (old == key) return;                    // duplicate
        h = (h + 1) & TAB_MASK;
    }
}

// 2a) per-chunk degree histogram in LDS (deg < DCAP).  [R14 exact]
__global__ void k_chunk_hist(const int* __restrict__ degree, int* __restrict__ hist,
                             int* __restrict__ chunkHist, int N) {
    __shared__ int sh[DCAP];
    int t = threadIdx.x;
    if (t < DCAP) sh[t] = 0;
    __syncthreads();
    int j = blockIdx.x * CHUNK + t;
    if (j < N) {
        int d = degree[j];
        if (d < DCAP) atomicAdd(&sh[d], 1);
        else          atomicAdd(&hist[d], 1);   // rare fallback path
    }
    __syncthreads();
    if (t < DCAP) chunkHist[blockIdx.x * DCAP + t] = sh[t];
}

// 2b) single block: totals + running per-chunk bases.
//     CHANGED: the serial RMW loop is batched 8-wide (read-ahead into
//     registers, then write) — 49 dependent L2 round-trips -> ~7.
__global__ void k_chunk_prefix(int* __restrict__ hist, int* __restrict__ chunkHist,
                               int numChunks) {
    __shared__ int stot[DCAP];
    int d = threadIdx.x;             // 0..DCAP-1
    int tot = 0;
    for (int c = 0; c < numChunks; ++c) tot += chunkHist[c * DCAP + d];
    stot[d] = tot;
    hist[d] = tot;                   // keeps the large-d base sums correct
    __syncthreads();
    int run = 0;
    for (int d2 = 0; d2 < d; ++d2) run += stot[d2];
    for (int c0 = 0; c0 < numChunks; c0 += 8) {
        int v[8];
        #pragma unroll
        for (int i = 0; i < 8; ++i)
            v[i] = (c0 + i < numChunks) ? chunkHist[(c0 + i) * DCAP + d] : 0;
        #pragma unroll
        for (int i = 0; i < 8; ++i)
            if (c0 + i < numChunks) { chunkHist[(c0 + i) * DCAP + d] = run; run += v[i]; }
    }
}

// 2c) merged pos: stable intra-chunk rank (deg < DCAP) + serial fallback.  [R14 exact]
__global__ __launch_bounds__(CHUNK) void k_pos(const int* __restrict__ degree,
                                               const int* __restrict__ chunkBase,
                                               const int* __restrict__ hist,
                                               int* __restrict__ pos,
                                               int N, int E, int numChunks) {
    int t = threadIdx.x;
    if ((int)blockIdx.x < numChunks) {
        __shared__ int sdeg[CHUNK];
        int j = blockIdx.x * CHUNK + t;
        int d = (j < N) ? degree[j] : -1;
        sdeg[t] = d;
        __syncthreads();
        if (j < N && d < DCAP && d >= 0) {
            int r = 0;
            for (int t2 = 0; t2 < t; ++t2) r += (sdeg[t2] == d);
            pos[j] = chunkBase[blockIdx.x * DCAP + d] + r;
        }
    } else {
        int d = DCAP + (blockIdx.x - numChunks) * CHUNK + t;
        if (d > E) return;
        if (hist[d] == 0) return;
        int base = 0;
        for (int d2 = 0; d2 < d; ++d2) base += hist[d2];
        int cnt = 0;
        for (int j = 0; j < N; ++j)
            if (degree[j] == d) pos[j] = base + cnt++;
    }
}

// 3) persistent-wave ballot-pack, permuted bit layout.  [R14 exact]
//    word g*8 + 2k+half, bit b  <->  float g*256 + 128*half + 4b + k.
#define PACK_DEPTH 8
__global__ __launch_bounds__(256) void k_pack_ballot(const float* __restrict__ W,
                                                     uint32_t* __restrict__ Wbits,
                                                     long long G) {
    long long wv0 = ((long long)blockIdx.x * 256 + threadIdx.x) >> 6;
    long long nwv = ((long long)gridDim.x * 256) >> 6;
    int lane = threadIdx.x & 63;
    int k = lane >> 1, half = lane & 1;          // meaningful when lane < 8
    const uintv4* W4 = (const uintv4*)W;
    for (long long gb = wv0 * PACK_DEPTH; gb < G; gb += nwv * PACK_DEPTH) {
        uintv4 u[PACK_DEPTH];
        #pragma unroll
        for (int s = 0; s < PACK_DEPTH; ++s) {
            long long g = gb + s;
            if (g >= G) g = G - 1;               // clamp: load stays in-bounds
            u[s] = W4[g * 64 + lane];
        }
        #pragma unroll
        for (int s = 0; s < PACK_DEPTH; ++s) {
            long long g = gb + s;
            unsigned long long m0 = __ballot((int)u[s].x < 0);
            unsigned long long m1 = __ballot((int)u[s].y < 0);
            unsigned long long m2 = __ballot((int)u[s].z < 0);
            unsigned long long m3 = __ballot((int)u[s].w < 0);
            if (g < G && lane < 8) {
                unsigned long long m = (k == 0) ? m0 : (k == 1) ? m1
                                     : (k == 2) ? m2 : m3;
                Wbits[g * 8 + lane] = half ? (uint32_t)(m >> 32) : (uint32_t)m;
            }
        }
    }
}

// 3-alt) linear-layout pack fallback (only if D % 256 != 0)
__global__ __launch_bounds__(256) void k_pack_linear(const float* __restrict__ W,
                                                     uint32_t* __restrict__ Wbits, long long NW) {
    long long widx = (long long)blockIdx.x * 256 + threadIdx.x;
    if (widx >= NW) return;
    const uintv4* src = (const uintv4*)(W + widx * 32);
    uint32_t word = 0;
    #pragma unroll
    for (int q = 0; q < 8; ++q) {
        uintv4 u = src[q];
        word |= (u.x >> 31) << (4 * q + 0);
        word |= (u.y >> 31) << (4 * q + 1);
        word |= (u.z >> 31) << (4 * q + 2);
        word |= (u.w >> 31) << (4 * q + 3);
    }
    Wbits[widx] = word;
}

// 4) accum: neg[w*32+d] += xor-popcount over unique edges; pos resolved here.
//    CHANGED: grid 256 — epilogue global atomics cut 4x (256 blocks x D),
//    gather phase unchanged (L2-resident, latency-tolerant over more passes).
__global__ __launch_bounds__(256) void k_accum_bits(const uint32_t* __restrict__ Wbits,
                                                    const int* __restrict__ pos,
                                                    const int* __restrict__ uA,
                                                    const int* __restrict__ uB,
                                                    const int* __restrict__ count,
                                                    int* __restrict__ neg, int D) {
    __shared__ int sneg[1024];
    int t = threadIdx.x, w = t & 31, slot = t >> 5;
    int wpr = D / 32;                       // requires D <= 1024
    for (int i = t; i < D; i += 256) sneg[i] = 0;
    __syncthreads();
    int cnt = *count;
    int cnts[32];
    #pragma unroll
    for (int d = 0; d < 32; ++d) cnts[d] = 0;
    if (w < wpr) {
        for (int base = blockIdx.x * 8; base < cnt; base += gridDim.x * 8) {
            int e = base + slot;
            if (e < cnt) {
                size_t ra = (size_t)pos[uA[e]] * wpr;
                size_t rb = (size_t)pos[uB[e]] * wpr;
                uint32_t x = Wbits[ra + w] ^ Wbits[rb + w];
                #pragma unroll
                for (int d = 0; d < 32; ++d) cnts[d] += (x >> d) & 1u;
            }
        }
        #pragma unroll
        for (int d = 0; d < 32; ++d) atomicAdd(&sneg[w * 32 + d], cnts[d]);
    }
    __syncthreads();
    for (int i = t; i < D; i += 256)
        if (sneg[i]) atomicAdd(&neg[i], sneg[i]);
}

// 5) out[d] = cnt - 2*neg[map(d)]  (exact integer, fits float32)  [R14 exact]
__global__ void k_finalize(const int* __restrict__ neg, const int* __restrict__ count,
                           float* __restrict__ out, int D, int permuted) {
    int d = blockIdx.x * blockDim.x + threadIdx.x;
    if (d >= D) return;
    int ni;
    if (permuted) {
        int off = d & 255, q = d >> 8;
        int k = off & 3, l = off >> 2, half = l >> 5, b = l & 31;
        ni = (q * 8 + 2 * k + half) * 32 + b;
    } else {
        ni = d;
    }
    out[d] = (float)(*count - 2 * neg[ni]);
}

static inline size_t align256(size_t x) { return (x + 255) & ~(size_t)255; }

extern "C" void kernel_launch(void* const* d_in, const int* in_sizes, int n_in,
                              void* d_out, int out_size, void* d_ws, size_t ws_size,
                              hipStream_t stream) {
    const float* W  = (const float*)d_in[0];
    const int*   ei = (const int*)d_in[1];
    const int D = out_size;               // 1024
    const int N = in_sizes[0] / D;        // 50000 (== num_nodes)
    const int E = in_sizes[1] / 2;        // 100000
    const int numChunks = (N + CHUNK - 1) / CHUNK;
    const long long ND = (long long)N * D;
    const long long NW = ND / 32;
    const long long G  = ND / 256;

    // zero-region: [degree | hist | count | neg] -> ONE memset
    char* p = (char*)d_ws;
    char* zbase = p;
    int* degree       = (int*)p;          p += align256((size_t)N * 4);
    int* hist         = (int*)p;          p += align256((size_t)(E + 1) * 4);
    int* count        = (int*)p;          p += 256;
    int* neg          = (int*)p;          p += align256((size_t)D * 4);
    size_t zbytes = (size_t)(p - zbase);
    int* chunkHist    = (int*)p;          p += align256((size_t)numChunks * DCAP * 4);
    int* pos          = (int*)p;          p += align256((size_t)N * 4);
    unsigned int* tab = (unsigned int*)p; p += (size_t)TAB_SIZE * 4;
    int* uA           = (int*)p;          p += align256((size_t)E * 4);
    int* uB           = (int*)p;          p += align256((size_t)E * 4);
    uint32_t* Wbits   = (uint32_t*)p;     p += align256((size_t)NW * 4);

    hipMemsetAsync(zbase, 0, zbytes, stream);
    hipMemsetAsync(tab, 0xFF, (size_t)TAB_SIZE * 4, stream);

    k_deg_ins<<<(E + 255) / 256, 256, 0, stream>>>(ei, degree, tab, uA, uB, count, E);
    k_chunk_hist<<<numChunks, CHUNK, 0, stream>>>(degree, hist, chunkHist, N);
    k_chunk_prefix<<<1, DCAP, 0, stream>>>(hist, chunkHist, numChunks);
    int nLargeBlocks = (E + 1 - DCAP + CHUNK - 1) / CHUNK;
    k_pos<<<numChunks + nLargeBlocks, CHUNK, 0, stream>>>(degree, chunkHist, hist,
                                                          pos, N, E, numChunks);

    int permuted = (D % 256 == 0);
    if (permuted) {
        k_pack_ballot<<<2048, 256, 0, stream>>>(W, Wbits, G);
    } else {
        k_pack_linear<<<(int)((NW + 255) / 256), 256, 0, stream>>>(W, Wbits, NW);
    }

    k_accum_bits<<<256, 256, 0, stream>>>(Wbits, pos, uA, uB, count, neg, D);
    k_finalize<<<(D + 255) / 256, 256, 0, stream>>>(neg, count, (float*)d_out, D, permuted);
}

// Round 16
// 136.705 us; speedup vs baseline: 1.0892x; 1.0892x over previous
//
#include <hip/hip_runtime.h>
#include <stdint.h>

#define DCAP   128
#define CHUNK  1024
#define LOG_TAB 18
#define TAB_SIZE (1u << LOG_TAB)
#define TAB_MASK (TAB_SIZE - 1u)
#define KEMPTY 0xFFFFFFFFu

typedef unsigned int uintv4 __attribute__((ext_vector_type(4)));

// 1) FUSED: in-degree (col) + undirected-dedup hash insert storing NODE ids
//    (pos resolved later in accum via broadcast L2 load).  [R14 exact]
__global__ void k_deg_ins(const int* __restrict__ ei, int* __restrict__ degree,
                          unsigned int* __restrict__ tab, int* __restrict__ uA,
                          int* __restrict__ uB, int* __restrict__ count, int E) {
    int e = blockIdx.x * blockDim.x + threadIdx.x;
    if (e >= E) return;
    int a = ei[e], b = ei[E + e];
    atomicAdd(&degree[b], 1);                      // bincount(edge_index[1])
    int r = min(a, b), c = max(a, b);
    unsigned int key = ((unsigned int)r << 16) | (unsigned int)c;  // N < 2^16
    unsigned int h = (key * 2654435761u) >> (32 - LOG_TAB);
    for (;;) {
        unsigned int old = atomicCAS(&tab[h], KEMPTY, key);
        if (old == KEMPTY) {                       // first occurrence
            int idx = atomicAdd(count, 1);
            uA[idx] = r; uB[idx] = c;
            return;
        }
        if (old == key) return;                    // duplicate
        h = (h + 1) & TAB_MASK;
    }
}

// 2a) per-chunk degree histogram in LDS (deg < DCAP).  [R14 exact]
__global__ void k_chunk_hist(const int* __restrict__ degree, int* __restrict__ hist,
                             int* __restrict__ chunkHist, int N) {
    __shared__ int sh[DCAP];
    int t = threadIdx.x;
    if (t < DCAP) sh[t] = 0;
    __syncthreads();
    int j = blockIdx.x * CHUNK + t;
    if (j < N) {
        int d = degree[j];
        if (d < DCAP) atomicAdd(&sh[d], 1);
        else          atomicAdd(&hist[d], 1);   // rare fallback path
    }
    __syncthreads();
    if (t < DCAP) chunkHist[blockIdx.x * DCAP + t] = sh[t];
}

// 2b) single block: totals + running per-chunk bases; RMW loop batched 8-wide
//     (identical semantics, fewer dependent L2 round-trips).  [R15, kept]
__global__ void k_chunk_prefix(int* __restrict__ hist, int* __restrict__ chunkHist,
                               int numChunks) {
    __shared__ int stot[DCAP];
    int d = threadIdx.x;             // 0..DCAP-1
    int tot = 0;
    for (int c = 0; c < numChunks; ++c) tot += chunkHist[c * DCAP + d];
    stot[d] = tot;
    hist[d] = tot;                   // keeps the large-d base sums correct
    __syncthreads();
    int run = 0;
    for (int d2 = 0; d2 < d; ++d2) run += stot[d2];
    for (int c0 = 0; c0 < numChunks; c0 += 8) {
        int v[8];
        #pragma unroll
        for (int i = 0; i < 8; ++i)
            v[i] = (c0 + i < numChunks) ? chunkHist[(c0 + i) * DCAP + d] : 0;
        #pragma unroll
        for (int i = 0; i < 8; ++i)
            if (c0 + i < numChunks) { chunkHist[(c0 + i) * DCAP + d] = run; run += v[i]; }
    }
}

// 2c) merged pos: stable intra-chunk rank (deg < DCAP) + serial fallback.  [R14 exact]
__global__ __launch_bounds__(CHUNK) void k_pos(const int* __restrict__ degree,
                                               const int* __restrict__ chunkBase,
                                               const int* __restrict__ hist,
                                               int* __restrict__ pos,
                                               int N, int E, int numChunks) {
    int t = threadIdx.x;
    if ((int)blockIdx.x < numChunks) {
        __shared__ int sdeg[CHUNK];
        int j = blockIdx.x * CHUNK + t;
        int d = (j < N) ? degree[j] : -1;
        sdeg[t] = d;
        __syncthreads();
        if (j < N && d < DCAP && d >= 0) {
            int r = 0;
            for (int t2 = 0; t2 < t; ++t2) r += (sdeg[t2] == d);
            pos[j] = chunkBase[blockIdx.x * DCAP + d] + r;
        }
    } else {
        int d = DCAP + (blockIdx.x - numChunks) * CHUNK + t;
        if (d > E) return;
        if (hist[d] == 0) return;
        int base = 0;
        for (int d2 = 0; d2 < d; ++d2) base += hist[d2];
        int cnt = 0;
        for (int j = 0; j < N; ++j)
            if (degree[j] == d) pos[j] = base + cnt++;
    }
}

// 3) persistent-wave ballot-pack, permuted bit layout.  [R14 exact]
//    word g*8 + 2k+half, bit b  <->  float g*256 + 128*half + 4b + k.
#define PACK_DEPTH 8
__global__ __launch_bounds__(256) void k_pack_ballot(const float* __restrict__ W,
                                                     uint32_t* __restrict__ Wbits,
                                                     long long G) {
    long long wv0 = ((long long)blockIdx.x * 256 + threadIdx.x) >> 6;
    long long nwv = ((long long)gridDim.x * 256) >> 6;
    int lane = threadIdx.x & 63;
    int k = lane >> 1, half = lane & 1;          // meaningful when lane < 8
    const uintv4* W4 = (const uintv4*)W;
    for (long long gb = wv0 * PACK_DEPTH; gb < G; gb += nwv * PACK_DEPTH) {
        uintv4 u[PACK_DEPTH];
        #pragma unroll
        for (int s = 0; s < PACK_DEPTH; ++s) {
            long long g = gb + s;
            if (g >= G) g = G - 1;               // clamp: load stays in-bounds
            u[s] = W4[g * 64 + lane];
        }
        #pragma unroll
        for (int s = 0; s < PACK_DEPTH; ++s) {
            long long g = gb + s;
            unsigned long long m0 = __ballot((int)u[s].x < 0);
            unsigned long long m1 = __ballot((int)u[s].y < 0);
            unsigned long long m2 = __ballot((int)u[s].z < 0);
            unsigned long long m3 = __ballot((int)u[s].w < 0);
            if (g < G && lane < 8) {
                unsigned long long m = (k == 0) ? m0 : (k == 1) ? m1
                                     : (k == 2) ? m2 : m3;
                Wbits[g * 8 + lane] = half ? (uint32_t)(m >> 32) : (uint32_t)m;
            }
        }
    }
}

// 3-alt) linear-layout pack fallback (only if D % 256 != 0)
__global__ __launch_bounds__(256) void k_pack_linear(const float* __restrict__ W,
                                                     uint32_t* __restrict__ Wbits, long long NW) {
    long long widx = (long long)blockIdx.x * 256 + threadIdx.x;
    if (widx >= NW) return;
    const uintv4* src = (const uintv4*)(W + widx * 32);
    uint32_t word = 0;
    #pragma unroll
    for (int q = 0; q < 8; ++q) {
        uintv4 u = src[q];
        word |= (u.x >> 31) << (4 * q + 0);
        word |= (u.y >> 31) << (4 * q + 1);
        word |= (u.z >> 31) << (4 * q + 2);
        word |= (u.w >> 31) << (4 * q + 3);
    }
    Wbits[widx] = word;
}

// 4) accum: neg[w*32+d] += xor-popcount over unique edges; pos resolved here.
//    Grid 1024 (R7/R14-proven: 4 blocks/CU hides the dependent-gather latency;
//    256 blocks = 1 block/CU regressed +11 µs in R15).
__global__ __launch_bounds__(256) void k_accum_bits(const uint32_t* __restrict__ Wbits,
                                                    const int* __restrict__ pos,
                                                    const int* __restrict__ uA,
                                                    const int* __restrict__ uB,
                                                    const int* __restrict__ count,
                                                    int* __restrict__ neg, int D) {
    __shared__ int sneg[1024];
    int t = threadIdx.x, w = t & 31, slot = t >> 5;
    int wpr = D / 32;                       // requires D <= 1024
    for (int i = t; i < D; i += 256) sneg[i] = 0;
    __syncthreads();
    int cnt = *count;
    int cnts[32];
    #pragma unroll
    for (int d = 0; d < 32; ++d) cnts[d] = 0;
    if (w < wpr) {
        for (int base = blockIdx.x * 8; base < cnt; base += gridDim.x * 8) {
            int e = base + slot;
            if (e < cnt) {
                size_t ra = (size_t)pos[uA[e]] * wpr;
                size_t rb = (size_t)pos[uB[e]] * wpr;
                uint32_t x = Wbits[ra + w] ^ Wbits[rb + w];
                #pragma unroll
                for (int d = 0; d < 32; ++d) cnts[d] += (x >> d) & 1u;
            }
        }
        #pragma unroll
        for (int d = 0; d < 32; ++d) atomicAdd(&sneg[w * 32 + d], cnts[d]);
    }
    __syncthreads();
    for (int i = t; i < D; i += 256)
        if (sneg[i]) atomicAdd(&neg[i], sneg[i]);
}

// 5) out[d] = cnt - 2*neg[map(d)]  (exact integer, fits float32)  [R14 exact]
__global__ void k_finalize(const int* __restrict__ neg, const int* __restrict__ count,
                           float* __restrict__ out, int D, int permuted) {
    int d = blockIdx.x * blockDim.x + threadIdx.x;
    if (d >= D) return;
    int ni;
    if (permuted) {
        int off = d & 255, q = d >> 8;
        int k = off & 3, l = off >> 2, half = l >> 5, b = l & 31;
        ni = (q * 8 + 2 * k + half) * 32 + b;
    } else {
        ni = d;
    }
    out[d] = (float)(*count - 2 * neg[ni]);
}

static inline size_t align256(size_t x) { return (x + 255) & ~(size_t)255; }

extern "C" void kernel_launch(void* const* d_in, const int* in_sizes, int n_in,
                              void* d_out, int out_size, void* d_ws, size_t ws_size,
                              hipStream_t stream) {
    const float* W  = (const float*)d_in[0];
    const int*   ei = (const int*)d_in[1];
    const int D = out_size;               // 1024
    const int N = in_sizes[0] / D;        // 50000 (== num_nodes)
    const int E = in_sizes[1] / 2;        // 100000
    const int numChunks = (N + CHUNK - 1) / CHUNK;
    const long long ND = (long long)N * D;
    const long long NW = ND / 32;
    const long long G  = ND / 256;

    // zero-region: [degree | hist | count | neg] -> ONE memset
    char* p = (char*)d_ws;
    char* zbase = p;
    int* degree       = (int*)p;          p += align256((size_t)N * 4);
    int* hist         = (int*)p;          p += align256((size_t)(E + 1) * 4);
    int* count        = (int*)p;          p += 256;
    int* neg          = (int*)p;          p += align256((size_t)D * 4);
    size_t zbytes = (size_t)(p - zbase);
    int* chunkHist    = (int*)p;          p += align256((size_t)numChunks * DCAP * 4);
    int* pos          = (int*)p;          p += align256((size_t)N * 4);
    unsigned int* tab = (unsigned int*)p; p += (size_t)TAB_SIZE * 4;
    int* uA           = (int*)p;          p += align256((size_t)E * 4);
    int* uB           = (int*)p;          p += align256((size_t)E * 4);
    uint32_t* Wbits   = (uint32_t*)p;     p += align256((size_t)NW * 4);

    hipMemsetAsync(zbase, 0, zbytes, stream);
    hipMemsetAsync(tab, 0xFF, (size_t)TAB_SIZE * 4, stream);

    k_deg_ins<<<(E + 255) / 256, 256, 0, stream>>>(ei, degree, tab, uA, uB, count, E);
    k_chunk_hist<<<numChunks, CHUNK, 0, stream>>>(degree, hist, chunkHist, N);
    k_chunk_prefix<<<1, DCAP, 0, stream>>>(hist, chunkHist, numChunks);
    int nLargeBlocks = (E + 1 - DCAP + CHUNK - 1) / CHUNK;
    k_pos<<<numChunks + nLargeBlocks, CHUNK, 0, stream>>>(degree, chunkHist, hist,
                                                          pos, N, E, numChunks);

    int permuted = (D % 256 == 0);
    if (permuted) {
        k_pack_ballot<<<2048, 256, 0, stream>>>(W, Wbits, G);
    } else {
        k_pack_linear<<<(int)((NW + 255) / 256), 256, 0, stream>>>(W, Wbits, NW);
    }

    k_accum_bits<<<1024, 256, 0, stream>>>(Wbits, pos, uA, uB, count, neg, D);
    k_finalize<<<(D + 255) / 256, 256, 0, stream>>>(neg, count, (float*)d_out, D, permuted);
}